// Round 12
// baseline (149.356 us; speedup 1.0000x reference)
//
#include <hip/hip_runtime.h>

#define B_ 8
#define C_ 512
#define N_ 2304
#define CQ 64

typedef float f32x4 __attribute__((ext_vector_type(4)));
typedef float f32x16 __attribute__((ext_vector_type(16)));
typedef short bf16x8 __attribute__((ext_vector_type(8)));
typedef unsigned short u16x4 __attribute__((ext_vector_type(4)));
typedef unsigned short u16x8 __attribute__((ext_vector_type(8)));
typedef int i32x4 __attribute__((ext_vector_type(4)));

__device__ __forceinline__ unsigned short f2bf(float f){
  union { float f; unsigned int u; } v; v.f = f;
  unsigned int r = (v.u + 0x7fffu + ((v.u >> 16) & 1u)) >> 16;
  return (unsigned short)r;
}

__device__ __forceinline__ void gload_lds16(const void* g, void* l){
  __builtin_amdgcn_global_load_lds(
      (const __attribute__((address_space(1))) unsigned int*)g,
      (__attribute__((address_space(3))) unsigned int*)l, 16, 0, 0);
}

// ---------------- W -> bf16, MFMA-A-frag BLOCKED layout ----------------
// chunk idx = ((ob*32 + cs)*64 + ln*2 + h)  (8 shorts per chunk)
// holds W[row = ob*32 + ln][col = cs*16 + h*8 .. +8), rows: 0-63 Q, 64-127 K, 128-639 V.
__global__ __launch_bounds__(256) void k_wcvt(const float* __restrict__ Wq,
                                              const float* __restrict__ Wk,
                                              const float* __restrict__ Wv,
                                              unsigned short* __restrict__ Wb){
  int idx = blockIdx.x*256 + threadIdx.x;         // 40960 chunks
  int h = idx & 1, ln = (idx >> 1) & 31, cs = (idx >> 6) & 31, ob = idx >> 11;
  int row = ob*32 + ln, col = cs*16 + h*8;
  const float* src;
  if (row < 64)       src = Wq + (size_t)row*512 + col;
  else if (row < 128) src = Wk + (size_t)(row-64)*512 + col;
  else                src = Wv + (size_t)(row-128)*512 + col;
  f32x4 v0 = *(const f32x4*)src;
  f32x4 v1 = *(const f32x4*)(src + 4);
  u16x8 o;
  #pragma unroll
  for (int j = 0; j < 4; j++){ o[j] = f2bf(v0[j]); o[4+j] = f2bf(v1[j]); }
  *(u16x8*)(Wb + (size_t)idx*8) = o;
}

// ---------------- fused prep: transpose + Q/K/V projections ----------------
__global__ __launch_bounds__(512) void k_prep(const float* __restrict__ x,
                                              const float* __restrict__ bq,
                                              const float* __restrict__ bk,
                                              const float* __restrict__ bv,
                                              const unsigned short* __restrict__ Wb,
                                              unsigned short* __restrict__ qw,
                                              unsigned short* __restrict__ kw,
                                              unsigned short* __restrict__ vw){
  __shared__ short xt_l[32*520];          // 33.3 KB
  __shared__ float scr[2*32*68];          // 17.4 KB

  int i = blockIdx.x; int b = i & 7; int nt = i >> 3;
  int n0 = nt*32;
  int t = threadIdx.x; int w = t >> 6; int l = t & 63;
  int h = l >> 5, ln = l & 31;
  const size_t bN = (size_t)b*N_;

  // ---- phase 1: stage x -> xt_l ----
  #pragma unroll
  for (int it = 0; it < 8; it++){
    int c = it*64 + (t >> 3);
    int n4 = (t & 7)*4;
    f32x4 v = *(const f32x4*)(x + ((size_t)b*C_ + c)*N_ + n0 + n4);
    #pragma unroll
    for (int j = 0; j < 4; j++) xt_l[(n4+j)*520 + c] = (short)f2bf(v[j]);
  }
  __syncthreads();

  // ---- phase 2: GEMMs (blocked-W frag reads: base + cs*512 shorts, lane-contig) ----
  const unsigned short* wlane = Wb + (size_t)(ln*2 + h)*8;
  const unsigned short* wv0 = wlane + (size_t)(4 + 2*w)*16384;
  const unsigned short* wv1 = wlane + (size_t)(5 + 2*w)*16384;
  const unsigned short* wqk = wlane + (size_t)w*16384;

  f32x16 vacc[2]; f32x16 qkacc;
  #pragma unroll
  for (int rr = 0; rr < 16; rr++){ vacc[0][rr]=0.f; vacc[1][rr]=0.f; qkacc[rr]=0.f; }

  #pragma unroll 8
  for (int cs = 0; cs < 32; cs++){
    bf16x8 bx = *(const bf16x8*)&xt_l[ln*520 + cs*16 + h*8];
    bf16x8 a0 = *(const bf16x8*)(wv0 + (size_t)cs*512);
    bf16x8 a1 = *(const bf16x8*)(wv1 + (size_t)cs*512);
    vacc[0] = __builtin_amdgcn_mfma_f32_32x32x16_bf16(a0, bx, vacc[0], 0, 0, 0);
    vacc[1] = __builtin_amdgcn_mfma_f32_32x32x16_bf16(a1, bx, vacc[1], 0, 0, 0);
    if (w < 4){
      bf16x8 aq = *(const bf16x8*)(wqk + (size_t)cs*512);
      qkacc = __builtin_amdgcn_mfma_f32_32x32x16_bf16(aq, bx, qkacc, 0, 0, 0);
    }
  }

  // ---- phase 3a: Q/K scratch + cooperative store ----
  if (w < 4){
    float* s = scr + ((w >> 1) ? 2176 : 0);
    int obase = (w & 1)*32;
    #pragma unroll
    for (int rr = 0; rr < 16; rr++){
      int o = obase + (rr & 3) + 8*(rr >> 2) + 4*h;
      s[ln*68 + o] = qkacc[rr];
    }
  }
  __syncthreads();

  if (t < 256){
    int isK = t >> 7;
    int tt = t & 127;
    int n = tt >> 2, j = tt & 3;
    const float* s = scr + (isK ? 2176 : 0);
    const float* bias = isK ? bk : bq;
    float vals[16]; float sm = 0.f;
    #pragma unroll
    for (int ii = 0; ii < 16; ii++){
      vals[ii] = s[n*68 + j*16 + ii] + bias[j*16 + ii];
      sm += vals[ii];
    }
    sm += __shfl_xor(sm, 1); sm += __shfl_xor(sm, 2);
    float mean = isK ? 0.f : sm * (1.f/64.f);
    float scl  = isK ? 1.f : (1.44269504089f/512.f);
    u16x8 h0, h1;
    #pragma unroll
    for (int ii = 0; ii < 8; ii++) h0[ii] = f2bf((vals[ii]   - mean)*scl);
    #pragma unroll
    for (int ii = 0; ii < 8; ii++) h1[ii] = f2bf((vals[8+ii] - mean)*scl);
    unsigned short* d = (isK ? kw : qw) + (bN + n0 + n)*CQ + j*16;
    *(u16x8*)d = h0;
    *(u16x8*)(d + 8) = h1;
  }
  __syncthreads();

  // ---- phase 3b: V epilogue, 4 rounds x 2 chunks of 64 o ----
  #pragma unroll
  for (int r = 0; r < 4; r++){
    if ((w >> 1) == r){
      float* s = scr + (w & 1)*2176;
      #pragma unroll
      for (int of = 0; of < 2; of++)
        #pragma unroll
        for (int rr = 0; rr < 16; rr++){
          int o = of*32 + (rr & 3) + 8*(rr >> 2) + 4*h;
          s[ln*68 + o] = vacc[of][rr];
        }
    }
    __syncthreads();
    {
      int ch = t >> 8;
      int tt = t & 255;
      int o = tt >> 2, jj = (tt >> 1) & 1, half = tt & 1;
      int og = (2*r + ch)*64 + o;
      const float* s = scr + ch*2176;
      float bvv = bv[og];
      u16x8 hv;
      #pragma unroll
      for (int ii = 0; ii < 8; ii++){
        int q2 = ((ii & 3) | ((ii & 4) << 1)) + half*4;
        hv[ii] = f2bf(s[(jj*16 + q2)*68 + o] + bvv);
      }
      *(u16x8*)(vw + ((size_t)b*C_ + og)*N_ + n0 + jj*16 + half*8) = hv;
    }
    __syncthreads();
  }
}

// ---------------- S + exp2 -> P (blocked frag-ready layout), K-prefetch pipelined ----------------
__global__ __launch_bounds__(256) void k_sexp(const unsigned short* __restrict__ qw,
                                              const unsigned short* __restrict__ kw,
                                              unsigned short* __restrict__ Pl,
                                              float* __restrict__ lsum_part,
                                              int b0, int bsh){
  int bid = blockIdx.x;
  int bl = bid & ((1 << bsh) - 1);
  int b = b0 + bl;
  int r = bid >> bsh;
  int ms = r & 3; int nt = r >> 2;
  int t = threadIdx.x; int w = t >> 6; int l = t & 63;
  int h = l >> 5, ln = l & 31;
  int nf = w & 1, mh = w >> 1;
  int n = nt*64 + nf*32 + ln;

  const unsigned short* qb = qw + ((size_t)b*N_ + n)*CQ + h*8;
  bf16x8 qf[4];
  #pragma unroll
  for (int kq = 0; kq < 4; kq++) qf[kq] = *(const bf16x8*)(qb + kq*16);

  int mb32base = ms*18 + mh*9;
  const unsigned short* ks0 = kw + ((size_t)b*N_ + ln)*CQ + h*8 + (size_t)mb32base*32*CQ;
  unsigned short* pb = Pl + ((size_t)bl*144*N_ + n)*16 + h*8;

  float lsum = 0.f;
  bf16x8 ka[4], kc[4];
  #pragma unroll
  for (int kq = 0; kq < 4; kq++) ka[kq] = *(const bf16x8*)(ks0 + kq*16);

  #define SEXP_BODY(MF, KF, KN, PFOFF)                                          \
  {                                                                             \
    _Pragma("unroll")                                                           \
    for (int kq = 0; kq < 4; kq++)                                              \
      KN[kq] = *(const bf16x8*)(ks0 + (size_t)(PFOFF)*32*CQ + kq*16);           \
    f32x16 sv;                                                                  \
    _Pragma("unroll")                                                           \
    for (int rr = 0; rr < 16; rr++) sv[rr] = 0.f;                               \
    _Pragma("unroll")                                                           \
    for (int kq = 0; kq < 4; kq++)                                              \
      sv = __builtin_amdgcn_mfma_f32_32x32x16_bf16(KF[kq], qf[kq], sv, 0, 0, 0);\
    float e[16];                                                                \
    _Pragma("unroll")                                                           \
    for (int rr = 0; rr < 16; rr++) e[rr] = exp2f(sv[rr]);                      \
    _Pragma("unroll")                                                           \
    for (int rr = 0; rr < 16; rr++) lsum += e[rr];                              \
    unsigned int pd[8];                                                         \
    _Pragma("unroll")                                                           \
    for (int j = 0; j < 8; j++)                                                 \
      asm("v_cvt_pk_bf16_f32 %0, %1, %2" : "=v"(pd[j]) : "v"(e[2*j]), "v"(e[2*j+1])); \
    i32x4 lo = (i32x4){(int)pd[0],(int)pd[1],(int)pd[2],(int)pd[3]};            \
    i32x4 hi = (i32x4){(int)pd[4],(int)pd[5],(int)pd[6],(int)pd[7]};            \
    unsigned short* d = pb + (size_t)((mb32base + (MF))*2)*N_*16;               \
    *(i32x4*)d = lo;                                                            \
    *(i32x4*)(d + (size_t)N_*16) = hi;                                          \
  }

  #pragma unroll
  for (int it = 0; it < 4; it++){
    SEXP_BODY(2*it,     ka, kc, 2*it + 1)
    SEXP_BODY(2*it + 1, kc, ka, 2*it + 2)
  }
  SEXP_BODY(8, ka, kc, 8)
  #undef SEXP_BODY

  lsum += __shfl_xor(lsum, 32);
  if (l < 32)
    lsum_part[((size_t)bl*8 + ms*2 + mh)*N_ + n] = lsum;
}

// ---------------- PV GEMM v4: barrier-free, wave-private A staging ----------------
// out[b][c][n] = gamma * (sum_m V[c][m] P[n][m]) / lsum[n] + x[b][c][n]
// 128c x 128n tile, 4 waves (wc=w&1 c-half, wn=w>>1 n-half), BK=64, 36 steps.
// Each wave stages ITS OWN [64c][64m] V region (2x dup) into private 2-buf LDS,
// 2 steps ahead; B (P) global->reg 3-buf 2-deep. NO s_barrier in the kernel:
// per-wave counted vmcnt self-pacing; waves drift -> stalls decorrelate.
__global__ __launch_bounds__(256) void k_pv(const unsigned short* __restrict__ vw,
                                            const unsigned short* __restrict__ Pl,
                                            const float* __restrict__ lsum_part,
                                            const float* __restrict__ x,
                                            const float* __restrict__ gamma_p,
                                            float* __restrict__ out,
                                            int b0, int bsh){
  __shared__ __attribute__((aligned(16))) short At[2][4][4096];   // 2 buf x 4 waves x 8KB

  int bid = blockIdx.x;
  int bl = bid & ((1 << bsh) - 1);
  int b = b0 + bl;
  int r = bid >> bsh;
  int cb = r & 3; int nb = r >> 2;
  int c0 = cb*128, n0g = nb*128;
  int t = threadIdx.x; int w = t >> 6; int l = t & 63;
  int h = l >> 5, ln = l & 31;
  int wc = w & 1, wn = w >> 1;

  // --- A staging: wave w covers its own rows [wc*64, wc*64+64) of the c-tile ---
  // granule (j*64 + l): row = j*8 + (l>>3), slot = l&7 holds data chunk ((l&7)-row)&7
  int gc = ((l & 7) - (l >> 3)) & 7;
  const unsigned short* asrc0 = vw + ((size_t)b*C_ + c0 + wc*64 + (l >> 3))*N_ + gc*8;
  short* aw[2] = { At[0][w], At[1][w] };
  // --- A frag read byte offsets within own region: row r = cf*32+ln ---
  int aro[2][4];
  #pragma unroll
  for (int cf = 0; cf < 2; cf++)
    #pragma unroll
    for (int mb = 0; mb < 4; mb++){
      int rr_ = cf*32 + ln;
      aro[cf][mb] = (rr_*8 + ((mb*2 + h + rr_) & 7)) * 16;
    }
  // --- B: per-lane offsets into Pl slab ---
  const unsigned short* Pb = Pl + (size_t)bl*144*N_*16;
  size_t bstep = (size_t)N_*16;
  int boff[2];
  #pragma unroll
  for (int nf = 0; nf < 2; nf++)
    boff[nf] = (n0g + wn*64 + nf*32 + ln)*16 + h*8;

  f32x16 acc[2][2];
  #pragma unroll
  for (int cf = 0; cf < 2; cf++)
    #pragma unroll
    for (int nf = 0; nf < 2; nf++)
      #pragma unroll
      for (int rr = 0; rr < 16; rr++) acc[cf][nf][rr] = 0.f;

  bf16x8 B0[2][4], B1[2][4], B2[2][4];

  // ---- prologue: A(0)->buf0, B(0)->B0, A(1)->buf1, B(1)->B1 (no barrier) ----
  #pragma unroll
  for (int j = 0; j < 8; j++)
    gload_lds16(asrc0 + (size_t)j*8*N_, aw[0] + j*512);
  #pragma unroll
  for (int nf = 0; nf < 2; nf++)
    #pragma unroll
    for (int mb = 0; mb < 4; mb++)
      B0[nf][mb] = *(const bf16x8*)(Pb + (size_t)mb*bstep + boff[nf]);
  #pragma unroll
  for (int j = 0; j < 8; j++)
    gload_lds16(asrc0 + (size_t)j*8*N_ + 64, aw[1] + j*512);
  #pragma unroll
  for (int nf = 0; nf < 2; nf++)
    #pragma unroll
    for (int mb = 0; mb < 4; mb++)
      B1[nf][mb] = *(const bf16x8*)(Pb + (size_t)(4 + mb)*bstep + boff[nf]);

  // Step t (A buf p = t&1): vmcnt(16) drains A(t)+B(t) (issued 2 steps ago);
  // read frags; lgkmcnt(0); overwrite buf p with A(t+2); load B(t+2); 16 MFMA.
  #define PV_STEP(KT, P, BC, BN)                                                \
  {                                                                             \
    asm volatile("s_waitcnt vmcnt(16)" ::: "memory");                           \
    __builtin_amdgcn_sched_barrier(0);                                          \
    const char* Ab = (const char*)aw[P];                                        \
    bf16x8 a_[2][4];                                                            \
    _Pragma("unroll")                                                           \
    for (int cf = 0; cf < 2; cf++)                                              \
      _Pragma("unroll")                                                         \
      for (int mb = 0; mb < 4; mb++)                                            \
        a_[cf][mb] = *(const bf16x8*)(Ab + aro[cf][mb]);                        \
    asm volatile("s_waitcnt lgkmcnt(0)" ::: "memory");                          \
    __builtin_amdgcn_sched_barrier(0);                                          \
    int m2 = ((KT) + 2 < 36) ? ((KT) + 2)*64 : 0;                               \
    _Pragma("unroll")                                                           \
    for (int j = 0; j < 8; j++)                                                 \
      gload_lds16(asrc0 + (size_t)j*8*N_ + m2, aw[P] + j*512);                  \
    {                                                                           \
      size_t mb2 = (size_t)((((KT) + 2 < 36) ? ((KT) + 2)*4 : 0));              \
      _Pragma("unroll")                                                         \
      for (int nf = 0; nf < 2; nf++)                                            \
        _Pragma("unroll")                                                       \
        for (int mb = 0; mb < 4; mb++)                                          \
          BN[nf][mb] = *(const bf16x8*)(Pb + (mb2 + mb)*bstep + boff[nf]);      \
    }                                                                           \
    __builtin_amdgcn_s_setprio(1);                                              \
    _Pragma("unroll")                                                           \
    for (int cf = 0; cf < 2; cf++)                                              \
      _Pragma("unroll")                                                         \
      for (int nf = 0; nf < 2; nf++)                                            \
        _Pragma("unroll")                                                       \
        for (int mb = 0; mb < 4; mb++)                                          \
          acc[cf][nf] = __builtin_amdgcn_mfma_f32_32x32x16_bf16(                \
              a_[cf][mb], BC[nf][mb], acc[cf][nf], 0, 0, 0);                    \
    __builtin_amdgcn_s_setprio(0);                                              \
  }

  for (int it = 0; it < 6; it++){
    int kt = it*6;
    PV_STEP(kt+0, 0, B0, B2)
    PV_STEP(kt+1, 1, B1, B0)
    PV_STEP(kt+2, 0, B2, B1)
    PV_STEP(kt+3, 1, B0, B2)
    PV_STEP(kt+4, 0, B1, B0)
    PV_STEP(kt+5, 1, B2, B1)
  }
  #undef PV_STEP

  float gmv = gamma_p[0];
  #pragma unroll
  for (int nf = 0; nf < 2; nf++){
    int n = n0g + wn*64 + nf*32 + ln;
    float s = 0.f;
    #pragma unroll
    for (int j = 0; j < 8; j++) s += lsum_part[((size_t)bl*8 + j)*N_ + n];
    float f = gmv / s;
    #pragma unroll
    for (int cf = 0; cf < 2; cf++){
      #pragma unroll
      for (int rr = 0; rr < 16; rr++){
        int c = c0 + wc*64 + cf*32 + (rr & 3) + 8*(rr >> 2) + 4*h;
        size_t idx = ((size_t)b*C_ + c)*N_ + n;
        out[idx] = acc[cf][nf][rr]*f + x[idx];
      }
    }
  }
}

extern "C" void kernel_launch(void* const* d_in, const int* in_sizes, int n_in,
                              void* d_out, int out_size, void* d_ws, size_t ws_size,
                              hipStream_t stream) {
  (void)in_sizes; (void)n_in; (void)out_size;
  const float* x  = (const float*)d_in[0];
  const float* Wq = (const float*)d_in[1];
  const float* bq = (const float*)d_in[2];
  const float* Wk = (const float*)d_in[3];
  const float* bk = (const float*)d_in[4];
  const float* Wv = (const float*)d_in[5];
  const float* bv = (const float*)d_in[6];
  const float* gm = (const float*)d_in[7];
  float* out = (float*)d_out;

  const size_t qw_b = (size_t)B_*N_*CQ*2;
  const size_t vw_b = (size_t)B_*C_*N_*2;
  const size_t wb_b = (size_t)640*512*2;

  int nbg = 8, bsh = 3;
  for (;;){
    size_t pl_b   = (size_t)nbg*144*N_*16*2;
    size_t lsum_b = (size_t)nbg*8*N_*4;
    size_t need   = pl_b + 2*qw_b + vw_b + lsum_b + wb_b;
    if (need <= ws_size || nbg == 1) break;
    nbg >>= 1; bsh--;
  }
  size_t pl_b   = (size_t)nbg*144*N_*16*2;
  size_t lsum_b = (size_t)nbg*8*N_*4;

  char* wsc = (char*)d_ws;
  unsigned short* Pl = (unsigned short*)wsc;
  unsigned short* qw = (unsigned short*)(wsc + pl_b);
  unsigned short* kw = (unsigned short*)(wsc + pl_b + qw_b);
  unsigned short* vw = (unsigned short*)(wsc + pl_b + 2*qw_b);
  float* lsum_part   = (float*)(wsc + pl_b + 2*qw_b + vw_b);
  unsigned short* Wb = (unsigned short*)(wsc + pl_b + 2*qw_b + vw_b + lsum_b);

  k_wcvt<<<160, 256, 0, stream>>>(Wq, Wk, Wv, Wb);
  k_prep<<<576, 512, 0, stream>>>(x, bq, bk, bv, Wb, qw, kw, vw);

  for (int b0 = 0; b0 < B_; b0 += nbg){
    k_sexp<<<144*nbg, 256, 0, stream>>>(qw, kw, Pl, lsum_part, b0, bsh);
    k_pv<<<72*nbg, 256, 0, stream>>>(vw, Pl, lsum_part, x, gm, out, b0, bsh);
  }
}

// Round 13
// 146.975 us; speedup vs baseline: 1.0162x; 1.0162x over previous
//
#include <hip/hip_runtime.h>

#define B_ 8
#define C_ 512
#define N_ 2304
#define CQ 64

typedef float f32x4 __attribute__((ext_vector_type(4)));
typedef float f32x16 __attribute__((ext_vector_type(16)));
typedef short bf16x8 __attribute__((ext_vector_type(8)));
typedef unsigned short u16x4 __attribute__((ext_vector_type(4)));
typedef unsigned short u16x8 __attribute__((ext_vector_type(8)));
typedef int i32x4 __attribute__((ext_vector_type(4)));

__device__ __forceinline__ unsigned short f2bf(float f){
  union { float f; unsigned int u; } v; v.f = f;
  unsigned int r = (v.u + 0x7fffu + ((v.u >> 16) & 1u)) >> 16;
  return (unsigned short)r;
}

__device__ __forceinline__ void gload_lds16(const void* g, void* l){
  __builtin_amdgcn_global_load_lds(
      (const __attribute__((address_space(1))) unsigned int*)g,
      (__attribute__((address_space(3))) unsigned int*)l, 16, 0, 0);
}

// ---------------- W -> bf16, MFMA-A-frag BLOCKED layout ----------------
__global__ __launch_bounds__(256) void k_wcvt(const float* __restrict__ Wq,
                                              const float* __restrict__ Wk,
                                              const float* __restrict__ Wv,
                                              unsigned short* __restrict__ Wb){
  int idx = blockIdx.x*256 + threadIdx.x;         // 40960 chunks
  int h = idx & 1, ln = (idx >> 1) & 31, cs = (idx >> 6) & 31, ob = idx >> 11;
  int row = ob*32 + ln, col = cs*16 + h*8;
  const float* src;
  if (row < 64)       src = Wq + (size_t)row*512 + col;
  else if (row < 128) src = Wk + (size_t)(row-64)*512 + col;
  else                src = Wv + (size_t)(row-128)*512 + col;
  f32x4 v0 = *(const f32x4*)src;
  f32x4 v1 = *(const f32x4*)(src + 4);
  u16x8 o;
  #pragma unroll
  for (int j = 0; j < 4; j++){ o[j] = f2bf(v0[j]); o[4+j] = f2bf(v1[j]); }
  *(u16x8*)(Wb + (size_t)idx*8) = o;
}

// ---------------- fused prep: transpose + Q/K/V projections ----------------
__global__ __launch_bounds__(512) void k_prep(const float* __restrict__ x,
                                              const float* __restrict__ bq,
                                              const float* __restrict__ bk,
                                              const float* __restrict__ bv,
                                              const unsigned short* __restrict__ Wb,
                                              unsigned short* __restrict__ qw,
                                              unsigned short* __restrict__ kw,
                                              unsigned short* __restrict__ vw){
  __shared__ short xt_l[32*520];          // 33.3 KB
  __shared__ float scr[2*32*68];          // 17.4 KB

  int i = blockIdx.x; int b = i & 7; int nt = i >> 3;
  int n0 = nt*32;
  int t = threadIdx.x; int w = t >> 6; int l = t & 63;
  int h = l >> 5, ln = l & 31;
  const size_t bN = (size_t)b*N_;

  // ---- phase 1: stage x -> xt_l ----
  #pragma unroll
  for (int it = 0; it < 8; it++){
    int c = it*64 + (t >> 3);
    int n4 = (t & 7)*4;
    f32x4 v = *(const f32x4*)(x + ((size_t)b*C_ + c)*N_ + n0 + n4);
    #pragma unroll
    for (int j = 0; j < 4; j++) xt_l[(n4+j)*520 + c] = (short)f2bf(v[j]);
  }
  __syncthreads();

  // ---- phase 2: GEMMs ----
  const unsigned short* wlane = Wb + (size_t)(ln*2 + h)*8;
  const unsigned short* wv0 = wlane + (size_t)(4 + 2*w)*16384;
  const unsigned short* wv1 = wlane + (size_t)(5 + 2*w)*16384;
  const unsigned short* wqk = wlane + (size_t)w*16384;

  f32x16 vacc[2]; f32x16 qkacc;
  #pragma unroll
  for (int rr = 0; rr < 16; rr++){ vacc[0][rr]=0.f; vacc[1][rr]=0.f; qkacc[rr]=0.f; }

  #pragma unroll 8
  for (int cs = 0; cs < 32; cs++){
    bf16x8 bx = *(const bf16x8*)&xt_l[ln*520 + cs*16 + h*8];
    bf16x8 a0 = *(const bf16x8*)(wv0 + (size_t)cs*512);
    bf16x8 a1 = *(const bf16x8*)(wv1 + (size_t)cs*512);
    vacc[0] = __builtin_amdgcn_mfma_f32_32x32x16_bf16(a0, bx, vacc[0], 0, 0, 0);
    vacc[1] = __builtin_amdgcn_mfma_f32_32x32x16_bf16(a1, bx, vacc[1], 0, 0, 0);
    if (w < 4){
      bf16x8 aq = *(const bf16x8*)(wqk + (size_t)cs*512);
      qkacc = __builtin_amdgcn_mfma_f32_32x32x16_bf16(aq, bx, qkacc, 0, 0, 0);
    }
  }

  // ---- phase 3a: Q/K scratch + cooperative store ----
  if (w < 4){
    float* s = scr + ((w >> 1) ? 2176 : 0);
    int obase = (w & 1)*32;
    #pragma unroll
    for (int rr = 0; rr < 16; rr++){
      int o = obase + (rr & 3) + 8*(rr >> 2) + 4*h;
      s[ln*68 + o] = qkacc[rr];
    }
  }
  __syncthreads();

  if (t < 256){
    int isK = t >> 7;
    int tt = t & 127;
    int n = tt >> 2, j = tt & 3;
    const float* s = scr + (isK ? 2176 : 0);
    const float* bias = isK ? bk : bq;
    float vals[16]; float sm = 0.f;
    #pragma unroll
    for (int ii = 0; ii < 16; ii++){
      vals[ii] = s[n*68 + j*16 + ii] + bias[j*16 + ii];
      sm += vals[ii];
    }
    sm += __shfl_xor(sm, 1); sm += __shfl_xor(sm, 2);
    float mean = isK ? 0.f : sm * (1.f/64.f);
    float scl  = isK ? 1.f : (1.44269504089f/512.f);
    u16x8 h0, h1;
    #pragma unroll
    for (int ii = 0; ii < 8; ii++) h0[ii] = f2bf((vals[ii]   - mean)*scl);
    #pragma unroll
    for (int ii = 0; ii < 8; ii++) h1[ii] = f2bf((vals[8+ii] - mean)*scl);
    unsigned short* d = (isK ? kw : qw) + (bN + n0 + n)*CQ + j*16;
    *(u16x8*)d = h0;
    *(u16x8*)(d + 8) = h1;
  }
  __syncthreads();

  // ---- phase 3b: V epilogue, 4 rounds x 2 chunks of 64 o ----
  #pragma unroll
  for (int r = 0; r < 4; r++){
    if ((w >> 1) == r){
      float* s = scr + (w & 1)*2176;
      #pragma unroll
      for (int of = 0; of < 2; of++)
        #pragma unroll
        for (int rr = 0; rr < 16; rr++){
          int o = of*32 + (rr & 3) + 8*(rr >> 2) + 4*h;
          s[ln*68 + o] = vacc[of][rr];
        }
    }
    __syncthreads();
    {
      int ch = t >> 8;
      int tt = t & 255;
      int o = tt >> 2, jj = (tt >> 1) & 1, half = tt & 1;
      int og = (2*r + ch)*64 + o;
      const float* s = scr + ch*2176;
      float bvv = bv[og];
      u16x8 hv;
      #pragma unroll
      for (int ii = 0; ii < 8; ii++){
        int q2 = ((ii & 3) | ((ii & 4) << 1)) + half*4;
        hv[ii] = f2bf(s[(jj*16 + q2)*68 + o] + bvv);
      }
      *(u16x8*)(vw + ((size_t)b*C_ + og)*N_ + n0 + jj*16 + half*8) = hv;
    }
    __syncthreads();
  }
}

// ---------------- S + exp2 -> P (blocked frag-ready layout), K-prefetch pipelined ----------------
__global__ __launch_bounds__(256) void k_sexp(const unsigned short* __restrict__ qw,
                                              const unsigned short* __restrict__ kw,
                                              unsigned short* __restrict__ Pl,
                                              float* __restrict__ lsum_part,
                                              int b0, int bsh){
  int bid = blockIdx.x;
  int bl = bid & ((1 << bsh) - 1);
  int b = b0 + bl;
  int r = bid >> bsh;
  int ms = r & 3; int nt = r >> 2;
  int t = threadIdx.x; int w = t >> 6; int l = t & 63;
  int h = l >> 5, ln = l & 31;
  int nf = w & 1, mh = w >> 1;
  int n = nt*64 + nf*32 + ln;

  const unsigned short* qb = qw + ((size_t)b*N_ + n)*CQ + h*8;
  bf16x8 qf[4];
  #pragma unroll
  for (int kq = 0; kq < 4; kq++) qf[kq] = *(const bf16x8*)(qb + kq*16);

  int mb32base = ms*18 + mh*9;
  const unsigned short* ks0 = kw + ((size_t)b*N_ + ln)*CQ + h*8 + (size_t)mb32base*32*CQ;
  unsigned short* pb = Pl + ((size_t)bl*144*N_ + n)*16 + h*8;

  float lsum = 0.f;
  bf16x8 ka[4], kc[4];
  #pragma unroll
  for (int kq = 0; kq < 4; kq++) ka[kq] = *(const bf16x8*)(ks0 + kq*16);

  #define SEXP_BODY(MF, KF, KN, PFOFF)                                          \
  {                                                                             \
    _Pragma("unroll")                                                           \
    for (int kq = 0; kq < 4; kq++)                                              \
      KN[kq] = *(const bf16x8*)(ks0 + (size_t)(PFOFF)*32*CQ + kq*16);           \
    f32x16 sv;                                                                  \
    _Pragma("unroll")                                                           \
    for (int rr = 0; rr < 16; rr++) sv[rr] = 0.f;                               \
    _Pragma("unroll")                                                           \
    for (int kq = 0; kq < 4; kq++)                                              \
      sv = __builtin_amdgcn_mfma_f32_32x32x16_bf16(KF[kq], qf[kq], sv, 0, 0, 0);\
    float e[16];                                                                \
    _Pragma("unroll")                                                           \
    for (int rr = 0; rr < 16; rr++) e[rr] = exp2f(sv[rr]);                      \
    _Pragma("unroll")                                                           \
    for (int rr = 0; rr < 16; rr++) lsum += e[rr];                              \
    unsigned int pd[8];                                                         \
    _Pragma("unroll")                                                           \
    for (int j = 0; j < 8; j++)                                                 \
      asm("v_cvt_pk_bf16_f32 %0, %1, %2" : "=v"(pd[j]) : "v"(e[2*j]), "v"(e[2*j+1])); \
    i32x4 lo = (i32x4){(int)pd[0],(int)pd[1],(int)pd[2],(int)pd[3]};            \
    i32x4 hi = (i32x4){(int)pd[4],(int)pd[5],(int)pd[6],(int)pd[7]};            \
    unsigned short* d = pb + (size_t)((mb32base + (MF))*2)*N_*16;               \
    *(i32x4*)d = lo;                                                            \
    *(i32x4*)(d + (size_t)N_*16) = hi;                                          \
  }

  #pragma unroll
  for (int it = 0; it < 4; it++){
    SEXP_BODY(2*it,     ka, kc, 2*it + 1)
    SEXP_BODY(2*it + 1, kc, ka, 2*it + 2)
  }
  SEXP_BODY(8, ka, kc, 8)
  #undef SEXP_BODY

  lsum += __shfl_xor(lsum, 32);
  if (l < 32)
    lsum_part[((size_t)bl*8 + ms*2 + mh)*N_ + n] = lsum;
}

// ---------------- PV GEMM v5: 256c x 128n, BK=64, R11 barrier pipeline ----------------
// out[b][c][n] = gamma * (sum_m V[c][m] P[n][m]) / lsum[n] + x[b][c][n]
// 8 waves (wc=w&3 c-quarter 64, wn=w>>2 n-half 64). 36 K-steps.
// A (V): LDS 3-buf [256c][64m] rotate-swizzled, staged 2 ahead (4 gload_lds/thr/step).
// B (P): global->reg 3-buf 2-deep (8 x 16B/thr/step, coalesced).
// One raw s_barrier/step + counted s_waitcnt vmcnt(20) lgkmcnt(0) (never drains).
__global__ __launch_bounds__(512, 1) void k_pv(const unsigned short* __restrict__ vw,
                                               const unsigned short* __restrict__ Pl,
                                               const float* __restrict__ lsum_part,
                                               const float* __restrict__ x,
                                               const float* __restrict__ gamma_p,
                                               float* __restrict__ out,
                                               int b0, int bsh){
  __shared__ __attribute__((aligned(16))) short At[3][256*64];   // 3 x 32 KB

  int bid = blockIdx.x;
  int bl = bid & ((1 << bsh) - 1);
  int b = b0 + bl;
  int r = bid >> bsh;
  int cb = r & 1; int nb = r >> 1;          // cb 0..1, nb 0..17
  int c0 = cb*256, n0g = nb*128;
  int t = threadIdx.x; int w = t >> 6; int l = t & 63;
  int h = l >> 5, ln = l & 31;
  int wc = w & 3, wn = w >> 2;

  // --- A staging: thread covers granules G = w*256 + j*64 + l (j=0..3) ---
  int gc = ((l & 7) - (l >> 3)) & 7;
  const unsigned short* asrc0 = vw + ((size_t)b*C_ + c0 + w*32 + (l >> 3))*N_ + gc*8;
  // --- A frag read byte offsets ---
  int aro[2][4];
  #pragma unroll
  for (int cf = 0; cf < 2; cf++)
    #pragma unroll
    for (int mb = 0; mb < 4; mb++){
      int row = wc*64 + cf*32 + ln;
      aro[cf][mb] = (row*8 + ((mb*2 + h + row) & 7)) * 16;
    }
  // --- B: per-lane offsets into Pl slab ---
  const unsigned short* Pb = Pl + (size_t)bl*144*N_*16;
  size_t bstep = (size_t)N_*16;
  int boff[2];
  #pragma unroll
  for (int nf = 0; nf < 2; nf++)
    boff[nf] = (n0g + wn*64 + nf*32 + ln)*16 + h*8;

  f32x16 acc[2][2];
  #pragma unroll
  for (int cf = 0; cf < 2; cf++)
    #pragma unroll
    for (int nf = 0; nf < 2; nf++)
      #pragma unroll
      for (int rr = 0; rr < 16; rr++) acc[cf][nf][rr] = 0.f;

  bf16x8 B0[2][4], B1[2][4], B2[2][4];

  // ---- prologue: stage A(0), A(1); load B(0), B(1) ----
  #pragma unroll
  for (int j = 0; j < 4; j++)
    gload_lds16(asrc0 + (size_t)j*8*N_, &At[0][w*2048 + j*512]);
  #pragma unroll
  for (int j = 0; j < 4; j++)
    gload_lds16(asrc0 + (size_t)j*8*N_ + 64, &At[1][w*2048 + j*512]);
  #pragma unroll
  for (int nf = 0; nf < 2; nf++)
    #pragma unroll
    for (int mb = 0; mb < 4; mb++)
      B0[nf][mb] = *(const bf16x8*)(Pb + (size_t)mb*bstep + boff[nf]);
  #pragma unroll
  for (int nf = 0; nf < 2; nf++)
    #pragma unroll
    for (int mb = 0; mb < 4; mb++)
      B1[nf][mb] = *(const bf16x8*)(Pb + (size_t)(4 + mb)*bstep + boff[nf]);
  asm volatile("s_waitcnt vmcnt(20)" ::: "memory");   // A(0) landed
  __builtin_amdgcn_s_barrier();
  __builtin_amdgcn_sched_barrier(0);

  // Step t: read A(t) frags, stage A(t+2), load B(t+2), MFMA with B(t).
  // In-flight at barrier: B(t+1)8 + A(t+2)4 + B(t+2)8 = 20 -> A(t+1) landed.
  #define PV_STEP(KT, RD, WR, BC, BN)                                           \
  {                                                                             \
    const char* Ab = (const char*)At[RD];                                       \
    bf16x8 a_[2][4];                                                            \
    _Pragma("unroll")                                                           \
    for (int cf = 0; cf < 2; cf++)                                              \
      _Pragma("unroll")                                                         \
      for (int mb = 0; mb < 4; mb++)                                            \
        a_[cf][mb] = *(const bf16x8*)(Ab + aro[cf][mb]);                        \
    int m2 = ((KT) + 2 < 36) ? ((KT) + 2)*64 : 0;                               \
    _Pragma("unroll")                                                           \
    for (int j = 0; j < 4; j++)                                                 \
      gload_lds16(asrc0 + (size_t)j*8*N_ + m2, &At[WR][w*2048 + j*512]);        \
    {                                                                           \
      size_t mb2 = (size_t)((((KT) + 2 < 36) ? ((KT) + 2)*4 : 0));              \
      _Pragma("unroll")                                                         \
      for (int nf = 0; nf < 2; nf++)                                            \
        _Pragma("unroll")                                                       \
        for (int mb = 0; mb < 4; mb++)                                          \
          BN[nf][mb] = *(const bf16x8*)(Pb + (mb2 + mb)*bstep + boff[nf]);      \
    }                                                                           \
    _Pragma("unroll")                                                           \
    for (int cf = 0; cf < 2; cf++)                                              \
      _Pragma("unroll")                                                         \
      for (int nf = 0; nf < 2; nf++)                                            \
        _Pragma("unroll")                                                       \
        for (int mb = 0; mb < 4; mb++)                                          \
          acc[cf][nf] = __builtin_amdgcn_mfma_f32_32x32x16_bf16(                \
              a_[cf][mb], BC[nf][mb], acc[cf][nf], 0, 0, 0);                    \
    asm volatile("s_waitcnt vmcnt(20) lgkmcnt(0)" ::: "memory");                \
    __builtin_amdgcn_s_barrier();                                               \
    __builtin_amdgcn_sched_barrier(0);                                          \
  }

  for (int it = 0; it < 6; it++){
    int kt = it*6;
    PV_STEP(kt+0, 0, 2, B0, B2)
    PV_STEP(kt+1, 1, 0, B1, B0)
    PV_STEP(kt+2, 2, 1, B2, B1)
    PV_STEP(kt+3, 0, 2, B0, B2)
    PV_STEP(kt+4, 1, 0, B1, B0)
    PV_STEP(kt+5, 2, 1, B2, B1)
  }
  #undef PV_STEP

  // ---- epilogue: out = gamma*(O/lsum) + x ----
  float gmv = gamma_p[0];
  #pragma unroll
  for (int nf = 0; nf < 2; nf++){
    int n = n0g + wn*64 + nf*32 + ln;
    float s = 0.f;
    #pragma unroll
    for (int j = 0; j < 8; j++) s += lsum_part[((size_t)bl*8 + j)*N_ + n];
    float f = gmv / s;
    #pragma unroll
    for (int cf = 0; cf < 2; cf++){
      #pragma unroll
      for (int rr = 0; rr < 16; rr++){
        int c = c0 + wc*64 + cf*32 + (rr & 3) + 8*(rr >> 2) + 4*h;
        size_t idx = ((size_t)b*C_ + c)*N_ + n;
        out[idx] = acc[cf][nf][rr]*f + x[idx];
      }
    }
  }
}

extern "C" void kernel_launch(void* const* d_in, const int* in_sizes, int n_in,
                              void* d_out, int out_size, void* d_ws, size_t ws_size,
                              hipStream_t stream) {
  (void)in_sizes; (void)n_in; (void)out_size;
  const float* x  = (const float*)d_in[0];
  const float* Wq = (const float*)d_in[1];
  const float* bq = (const float*)d_in[2];
  const float* Wk = (const float*)d_in[3];
  const float* bk = (const float*)d_in[4];
  const float* Wv = (const float*)d_in[5];
  const float* bv = (const float*)d_in[6];
  const float* gm = (const float*)d_in[7];
  float* out = (float*)d_out;

  const size_t qw_b = (size_t)B_*N_*CQ*2;
  const size_t vw_b = (size_t)B_*C_*N_*2;
  const size_t wb_b = (size_t)640*512*2;

  int nbg = 8, bsh = 3;
  for (;;){
    size_t pl_b   = (size_t)nbg*144*N_*16*2;
    size_t lsum_b = (size_t)nbg*8*N_*4;
    size_t need   = pl_b + 2*qw_b + vw_b + lsum_b + wb_b;
    if (need <= ws_size || nbg == 1) break;
    nbg >>= 1; bsh--;
  }
  size_t pl_b   = (size_t)nbg*144*N_*16*2;
  size_t lsum_b = (size_t)nbg*8*N_*4;

  char* wsc = (char*)d_ws;
  unsigned short* Pl = (unsigned short*)wsc;
  unsigned short* qw = (unsigned short*)(wsc + pl_b);
  unsigned short* kw = (unsigned short*)(wsc + pl_b + qw_b);
  unsigned short* vw = (unsigned short*)(wsc + pl_b + 2*qw_b);
  float* lsum_part   = (float*)(wsc + pl_b + 2*qw_b + vw_b);
  unsigned short* Wb = (unsigned short*)(wsc + pl_b + 2*qw_b + vw_b + lsum_b);

  k_wcvt<<<160, 256, 0, stream>>>(Wq, Wk, Wv, Wb);
  k_prep<<<576, 512, 0, stream>>>(x, bq, bk, bv, Wb, qw, kw, vw);

  for (int b0 = 0; b0 < B_; b0 += nbg){
    k_sexp<<<144*nbg, 256, 0, stream>>>(qw, kw, Pl, lsum_part, b0, bsh);
    k_pv<<<36*nbg, 512, 0, stream>>>(vw, Pl, lsum_part, x, gm, out, b0, bsh);
  }
}

// Round 14
// 128.849 us; speedup vs baseline: 1.1591x; 1.1407x over previous
//
#include <hip/hip_runtime.h>

#define B_ 8
#define C_ 512
#define N_ 2304
#define CQ 64

typedef float f32x4 __attribute__((ext_vector_type(4)));
typedef float f32x16 __attribute__((ext_vector_type(16)));
typedef short bf16x8 __attribute__((ext_vector_type(8)));
typedef unsigned short u16x4 __attribute__((ext_vector_type(4)));
typedef unsigned short u16x8 __attribute__((ext_vector_type(8)));
typedef int i32x4 __attribute__((ext_vector_type(4)));

__device__ __forceinline__ unsigned short f2bf(float f){
  union { float f; unsigned int u; } v; v.f = f;
  unsigned int r = (v.u + 0x7fffu + ((v.u >> 16) & 1u)) >> 16;
  return (unsigned short)r;
}

__device__ __forceinline__ void gload_lds16(const void* g, void* l){
  __builtin_amdgcn_global_load_lds(
      (const __attribute__((address_space(1))) unsigned int*)g,
      (__attribute__((address_space(3))) unsigned int*)l, 16, 0, 0);
}

// ---------------- W -> bf16, MFMA-A-frag BLOCKED layout ----------------
__global__ __launch_bounds__(256) void k_wcvt(const float* __restrict__ Wq,
                                              const float* __restrict__ Wk,
                                              const float* __restrict__ Wv,
                                              unsigned short* __restrict__ Wb){
  int idx = blockIdx.x*256 + threadIdx.x;         // 40960 chunks
  int h = idx & 1, ln = (idx >> 1) & 31, cs = (idx >> 6) & 31, ob = idx >> 11;
  int row = ob*32 + ln, col = cs*16 + h*8;
  const float* src;
  if (row < 64)       src = Wq + (size_t)row*512 + col;
  else if (row < 128) src = Wk + (size_t)(row-64)*512 + col;
  else                src = Wv + (size_t)(row-128)*512 + col;
  f32x4 v0 = *(const f32x4*)src;
  f32x4 v1 = *(const f32x4*)(src + 4);
  u16x8 o;
  #pragma unroll
  for (int j = 0; j < 4; j++){ o[j] = f2bf(v0[j]); o[4+j] = f2bf(v1[j]); }
  *(u16x8*)(Wb + (size_t)idx*8) = o;
}

// ---------------- fused prep: transpose + Q/K/V projections ----------------
__global__ __launch_bounds__(512) void k_prep(const float* __restrict__ x,
                                              const float* __restrict__ bq,
                                              const float* __restrict__ bk,
                                              const float* __restrict__ bv,
                                              const unsigned short* __restrict__ Wb,
                                              unsigned short* __restrict__ qw,
                                              unsigned short* __restrict__ kw,
                                              unsigned short* __restrict__ vw){
  __shared__ short xt_l[32*520];          // 33.3 KB
  __shared__ float scr[2*32*68];          // 17.4 KB

  int i = blockIdx.x; int b = i & 7; int nt = i >> 3;
  int n0 = nt*32;
  int t = threadIdx.x; int w = t >> 6; int l = t & 63;
  int h = l >> 5, ln = l & 31;
  const size_t bN = (size_t)b*N_;

  // ---- phase 1: stage x -> xt_l ----
  #pragma unroll
  for (int it = 0; it < 8; it++){
    int c = it*64 + (t >> 3);
    int n4 = (t & 7)*4;
    f32x4 v = *(const f32x4*)(x + ((size_t)b*C_ + c)*N_ + n0 + n4);
    #pragma unroll
    for (int j = 0; j < 4; j++) xt_l[(n4+j)*520 + c] = (short)f2bf(v[j]);
  }
  __syncthreads();

  // ---- phase 2: GEMMs ----
  const unsigned short* wlane = Wb + (size_t)(ln*2 + h)*8;
  const unsigned short* wv0 = wlane + (size_t)(4 + 2*w)*16384;
  const unsigned short* wv1 = wlane + (size_t)(5 + 2*w)*16384;
  const unsigned short* wqk = wlane + (size_t)w*16384;

  f32x16 vacc[2]; f32x16 qkacc;
  #pragma unroll
  for (int rr = 0; rr < 16; rr++){ vacc[0][rr]=0.f; vacc[1][rr]=0.f; qkacc[rr]=0.f; }

  #pragma unroll 8
  for (int cs = 0; cs < 32; cs++){
    bf16x8 bx = *(const bf16x8*)&xt_l[ln*520 + cs*16 + h*8];
    bf16x8 a0 = *(const bf16x8*)(wv0 + (size_t)cs*512);
    bf16x8 a1 = *(const bf16x8*)(wv1 + (size_t)cs*512);
    vacc[0] = __builtin_amdgcn_mfma_f32_32x32x16_bf16(a0, bx, vacc[0], 0, 0, 0);
    vacc[1] = __builtin_amdgcn_mfma_f32_32x32x16_bf16(a1, bx, vacc[1], 0, 0, 0);
    if (w < 4){
      bf16x8 aq = *(const bf16x8*)(wqk + (size_t)cs*512);
      qkacc = __builtin_amdgcn_mfma_f32_32x32x16_bf16(aq, bx, qkacc, 0, 0, 0);
    }
  }

  // ---- phase 3a: Q/K scratch + cooperative store ----
  if (w < 4){
    float* s = scr + ((w >> 1) ? 2176 : 0);
    int obase = (w & 1)*32;
    #pragma unroll
    for (int rr = 0; rr < 16; rr++){
      int o = obase + (rr & 3) + 8*(rr >> 2) + 4*h;
      s[ln*68 + o] = qkacc[rr];
    }
  }
  __syncthreads();

  if (t < 256){
    int isK = t >> 7;
    int tt = t & 127;
    int n = tt >> 2, j = tt & 3;
    const float* s = scr + (isK ? 2176 : 0);
    const float* bias = isK ? bk : bq;
    float vals[16]; float sm = 0.f;
    #pragma unroll
    for (int ii = 0; ii < 16; ii++){
      vals[ii] = s[n*68 + j*16 + ii] + bias[j*16 + ii];
      sm += vals[ii];
    }
    sm += __shfl_xor(sm, 1); sm += __shfl_xor(sm, 2);
    float mean = isK ? 0.f : sm * (1.f/64.f);
    float scl  = isK ? 1.f : (1.44269504089f/512.f);
    u16x8 h0, h1;
    #pragma unroll
    for (int ii = 0; ii < 8; ii++) h0[ii] = f2bf((vals[ii]   - mean)*scl);
    #pragma unroll
    for (int ii = 0; ii < 8; ii++) h1[ii] = f2bf((vals[8+ii] - mean)*scl);
    unsigned short* d = (isK ? kw : qw) + (bN + n0 + n)*CQ + j*16;
    *(u16x8*)d = h0;
    *(u16x8*)(d + 8) = h1;
  }
  __syncthreads();

  // ---- phase 3b: V epilogue, 4 rounds x 2 chunks of 64 o ----
  #pragma unroll
  for (int r = 0; r < 4; r++){
    if ((w >> 1) == r){
      float* s = scr + (w & 1)*2176;
      #pragma unroll
      for (int of = 0; of < 2; of++)
        #pragma unroll
        for (int rr = 0; rr < 16; rr++){
          int o = of*32 + (rr & 3) + 8*(rr >> 2) + 4*h;
          s[ln*68 + o] = vacc[of][rr];
        }
    }
    __syncthreads();
    {
      int ch = t >> 8;
      int tt = t & 255;
      int o = tt >> 2, jj = (tt >> 1) & 1, half = tt & 1;
      int og = (2*r + ch)*64 + o;
      const float* s = scr + ch*2176;
      float bvv = bv[og];
      u16x8 hv;
      #pragma unroll
      for (int ii = 0; ii < 8; ii++){
        int q2 = ((ii & 3) | ((ii & 4) << 1)) + half*4;
        hv[ii] = f2bf(s[(jj*16 + q2)*68 + o] + bvv);
      }
      *(u16x8*)(vw + ((size_t)b*C_ + og)*N_ + n0 + jj*16 + half*8) = hv;
    }
    __syncthreads();
  }
}

// ---------------- S + exp2 -> P (blocked frag-ready layout), K-prefetch pipelined ----------------
__global__ __launch_bounds__(256) void k_sexp(const unsigned short* __restrict__ qw,
                                              const unsigned short* __restrict__ kw,
                                              unsigned short* __restrict__ Pl,
                                              float* __restrict__ lsum_part,
                                              int b0, int bsh){
  int bid = blockIdx.x;
  int bl = bid & ((1 << bsh) - 1);
  int b = b0 + bl;
  int r = bid >> bsh;
  int ms = r & 3; int nt = r >> 2;
  int t = threadIdx.x; int w = t >> 6; int l = t & 63;
  int h = l >> 5, ln = l & 31;
  int nf = w & 1, mh = w >> 1;
  int n = nt*64 + nf*32 + ln;

  const unsigned short* qb = qw + ((size_t)b*N_ + n)*CQ + h*8;
  bf16x8 qf[4];
  #pragma unroll
  for (int kq = 0; kq < 4; kq++) qf[kq] = *(const bf16x8*)(qb + kq*16);

  int mb32base = ms*18 + mh*9;
  const unsigned short* ks0 = kw + ((size_t)b*N_ + ln)*CQ + h*8 + (size_t)mb32base*32*CQ;
  unsigned short* pb = Pl + ((size_t)bl*144*N_ + n)*16 + h*8;

  float lsum = 0.f;
  bf16x8 ka[4], kc[4];
  #pragma unroll
  for (int kq = 0; kq < 4; kq++) ka[kq] = *(const bf16x8*)(ks0 + kq*16);

  #define SEXP_BODY(MF, KF, KN, PFOFF)                                          \
  {                                                                             \
    _Pragma("unroll")                                                           \
    for (int kq = 0; kq < 4; kq++)                                              \
      KN[kq] = *(const bf16x8*)(ks0 + (size_t)(PFOFF)*32*CQ + kq*16);           \
    f32x16 sv;                                                                  \
    _Pragma("unroll")                                                           \
    for (int rr = 0; rr < 16; rr++) sv[rr] = 0.f;                               \
    _Pragma("unroll")                                                           \
    for (int kq = 0; kq < 4; kq++)                                              \
      sv = __builtin_amdgcn_mfma_f32_32x32x16_bf16(KF[kq], qf[kq], sv, 0, 0, 0);\
    float e[16];                                                                \
    _Pragma("unroll")                                                           \
    for (int rr = 0; rr < 16; rr++) e[rr] = exp2f(sv[rr]);                      \
    _Pragma("unroll")                                                           \
    for (int rr = 0; rr < 16; rr++) lsum += e[rr];                              \
    unsigned int pd[8];                                                         \
    _Pragma("unroll")                                                           \
    for (int j = 0; j < 8; j++)                                                 \
      asm("v_cvt_pk_bf16_f32 %0, %1, %2" : "=v"(pd[j]) : "v"(e[2*j]), "v"(e[2*j+1])); \
    i32x4 lo = (i32x4){(int)pd[0],(int)pd[1],(int)pd[2],(int)pd[3]};            \
    i32x4 hi = (i32x4){(int)pd[4],(int)pd[5],(int)pd[6],(int)pd[7]};            \
    unsigned short* d = pb + (size_t)((mb32base + (MF))*2)*N_*16;               \
    *(i32x4*)d = lo;                                                            \
    *(i32x4*)(d + (size_t)N_*16) = hi;                                          \
  }

  #pragma unroll
  for (int it = 0; it < 4; it++){
    SEXP_BODY(2*it,     ka, kc, 2*it + 1)
    SEXP_BODY(2*it + 1, kc, ka, 2*it + 2)
  }
  SEXP_BODY(8, ka, kc, 8)
  #undef SEXP_BODY

  lsum += __shfl_xor(lsum, 32);
  if (l < 32)
    lsum_part[((size_t)bl*8 + ms*2 + mh)*N_ + n] = lsum;
}

// ---------------- PV GEMM v6: 128c x 64n, BK=64, R11 pipeline, 3 blocks/CU ----------------
// out[b][c][n] = gamma * (sum_m V[c][m] P[n][m]) / lsum[n] + x[b][c][n]
// 4 waves (wc=w&1: c-half 64, wn=w>>1: n-half 32). 36 K-steps, grid 144/batch.
// A (V): LDS 3-buf [128c][64m] rotate-swizzled, staged 2 ahead (4 gload_lds/thr/step).
// B (P): global->reg 3-buf 2-deep (4 x 16B/thr/step, coalesced).
// One raw s_barrier/step + counted s_waitcnt vmcnt(12) lgkmcnt(0) (never drains).
__global__ __launch_bounds__(256, 1) void k_pv(const unsigned short* __restrict__ vw,
                                               const unsigned short* __restrict__ Pl,
                                               const float* __restrict__ lsum_part,
                                               const float* __restrict__ x,
                                               const float* __restrict__ gamma_p,
                                               float* __restrict__ out,
                                               int b0, int bsh){
  __shared__ __attribute__((aligned(16))) short At[3][128*64];   // 3 x 16 KB

  int bid = blockIdx.x;
  int bl = bid & ((1 << bsh) - 1);
  int b = b0 + bl;
  int r = bid >> bsh;
  int cb = r & 3; int nb = r >> 2;          // cb 0..3, nb 0..35
  int c0 = cb*128, n0g = nb*64;
  int t = threadIdx.x; int w = t >> 6; int l = t & 63;
  int h = l >> 5, ln = l & 31;
  int wc = w & 1, wn = w >> 1;

  // --- A staging: thread covers granules G = w*256 + j*64 + l (j=0..3) ---
  int gc = ((l & 7) - (l >> 3)) & 7;
  const unsigned short* asrc0 = vw + ((size_t)b*C_ + c0 + w*32 + (l >> 3))*N_ + gc*8;
  // --- A frag read byte offsets ---
  int aro[2][4];
  #pragma unroll
  for (int cf = 0; cf < 2; cf++)
    #pragma unroll
    for (int mb = 0; mb < 4; mb++){
      int row = wc*64 + cf*32 + ln;
      aro[cf][mb] = (row*8 + ((mb*2 + h + row) & 7)) * 16;
    }
  // --- B: per-lane offset into Pl slab (one 32-n slot per wave) ---
  const unsigned short* Pb = Pl + (size_t)bl*144*N_*16;
  size_t bstep = (size_t)N_*16;              // one 16-m block (shorts)
  int boff = (n0g + wn*32 + ln)*16 + h*8;

  f32x16 acc[2];
  #pragma unroll
  for (int cf = 0; cf < 2; cf++)
    #pragma unroll
    for (int rr = 0; rr < 16; rr++) acc[cf][rr] = 0.f;

  bf16x8 B0[4], B1[4], B2[4];

  // ---- prologue: stage A(0), load B(0); stage A(1), load B(1) ----
  #pragma unroll
  for (int j = 0; j < 4; j++)
    gload_lds16(asrc0 + (size_t)j*8*N_, &At[0][w*2048 + j*512]);
  #pragma unroll
  for (int mb = 0; mb < 4; mb++)
    B0[mb] = *(const bf16x8*)(Pb + (size_t)mb*bstep + boff);
  #pragma unroll
  for (int j = 0; j < 4; j++)
    gload_lds16(asrc0 + (size_t)j*8*N_ + 64, &At[1][w*2048 + j*512]);
  #pragma unroll
  for (int mb = 0; mb < 4; mb++)
    B1[mb] = *(const bf16x8*)(Pb + (size_t)(4 + mb)*bstep + boff);
  asm volatile("s_waitcnt vmcnt(12)" ::: "memory");   // A(0) landed
  __builtin_amdgcn_s_barrier();
  __builtin_amdgcn_sched_barrier(0);

  // Step t: read A(t) frags, stage A(t+2), load B(t+2), MFMA with B(t).
  // In-flight at barrier: B(t+1)4 + A(t+2)4 + B(t+2)4 = 12 -> A(t+1) landed.
  #define PV_STEP(KT, RD, WR, BC, BN)                                           \
  {                                                                             \
    const char* Ab = (const char*)At[RD];                                       \
    bf16x8 a_[2][4];                                                            \
    _Pragma("unroll")                                                           \
    for (int cf = 0; cf < 2; cf++)                                              \
      _Pragma("unroll")                                                         \
      for (int mb = 0; mb < 4; mb++)                                            \
        a_[cf][mb] = *(const bf16x8*)(Ab + aro[cf][mb]);                        \
    int m2 = ((KT) + 2 < 36) ? ((KT) + 2)*64 : 0;                               \
    _Pragma("unroll")                                                           \
    for (int j = 0; j < 4; j++)                                                 \
      gload_lds16(asrc0 + (size_t)j*8*N_ + m2, &At[WR][w*2048 + j*512]);        \
    {                                                                           \
      size_t mb2 = (size_t)((((KT) + 2 < 36) ? ((KT) + 2)*4 : 0));              \
      _Pragma("unroll")                                                         \
      for (int mb = 0; mb < 4; mb++)                                            \
        BN[mb] = *(const bf16x8*)(Pb + (mb2 + mb)*bstep + boff);                \
    }                                                                           \
    _Pragma("unroll")                                                           \
    for (int cf = 0; cf < 2; cf++)                                              \
      _Pragma("unroll")                                                         \
      for (int mb = 0; mb < 4; mb++)                                            \
        acc[cf] = __builtin_amdgcn_mfma_f32_32x32x16_bf16(                      \
            a_[cf][mb], BC[mb], acc[cf], 0, 0, 0);                              \
    asm volatile("s_waitcnt vmcnt(12) lgkmcnt(0)" ::: "memory");                \
    __builtin_amdgcn_s_barrier();                                               \
    __builtin_amdgcn_sched_barrier(0);                                          \
  }

  for (int it = 0; it < 6; it++){
    int kt = it*6;
    PV_STEP(kt+0, 0, 2, B0, B2)
    PV_STEP(kt+1, 1, 0, B1, B0)
    PV_STEP(kt+2, 2, 1, B2, B1)
    PV_STEP(kt+3, 0, 2, B0, B2)
    PV_STEP(kt+4, 1, 0, B1, B0)
    PV_STEP(kt+5, 2, 1, B2, B1)
  }
  #undef PV_STEP

  // ---- epilogue: out = gamma*(O/lsum) + x ----
  float gmv = gamma_p[0];
  {
    int n = n0g + wn*32 + ln;
    float s = 0.f;
    #pragma unroll
    for (int j = 0; j < 8; j++) s += lsum_part[((size_t)bl*8 + j)*N_ + n];
    float f = gmv / s;
    #pragma unroll
    for (int cf = 0; cf < 2; cf++){
      #pragma unroll
      for (int rr = 0; rr < 16; rr++){
        int c = c0 + wc*64 + cf*32 + (rr & 3) + 8*(rr >> 2) + 4*h;
        size_t idx = ((size_t)b*C_ + c)*N_ + n;
        out[idx] = acc[cf][rr]*f + x[idx];
      }
    }
  }
}

extern "C" void kernel_launch(void* const* d_in, const int* in_sizes, int n_in,
                              void* d_out, int out_size, void* d_ws, size_t ws_size,
                              hipStream_t stream) {
  (void)in_sizes; (void)n_in; (void)out_size;
  const float* x  = (const float*)d_in[0];
  const float* Wq = (const float*)d_in[1];
  const float* bq = (const float*)d_in[2];
  const float* Wk = (const float*)d_in[3];
  const float* bk = (const float*)d_in[4];
  const float* Wv = (const float*)d_in[5];
  const float* bv = (const float*)d_in[6];
  const float* gm = (const float*)d_in[7];
  float* out = (float*)d_out;

  const size_t qw_b = (size_t)B_*N_*CQ*2;
  const size_t vw_b = (size_t)B_*C_*N_*2;
  const size_t wb_b = (size_t)640*512*2;

  int nbg = 8, bsh = 3;
  for (;;){
    size_t pl_b   = (size_t)nbg*144*N_*16*2;
    size_t lsum_b = (size_t)nbg*8*N_*4;
    size_t need   = pl_b + 2*qw_b + vw_b + lsum_b + wb_b;
    if (need <= ws_size || nbg == 1) break;
    nbg >>= 1; bsh--;
  }
  size_t pl_b   = (size_t)nbg*144*N_*16*2;
  size_t lsum_b = (size_t)nbg*8*N_*4;

  char* wsc = (char*)d_ws;
  unsigned short* Pl = (unsigned short*)wsc;
  unsigned short* qw = (unsigned short*)(wsc + pl_b);
  unsigned short* kw = (unsigned short*)(wsc + pl_b + qw_b);
  unsigned short* vw = (unsigned short*)(wsc + pl_b + 2*qw_b);
  float* lsum_part   = (float*)(wsc + pl_b + 2*qw_b + vw_b);
  unsigned short* Wb = (unsigned short*)(wsc + pl_b + 2*qw_b + vw_b + lsum_b);

  k_wcvt<<<160, 256, 0, stream>>>(Wq, Wk, Wv, Wb);
  k_prep<<<576, 512, 0, stream>>>(x, bq, bk, bv, Wb, qw, kw, vw);

  for (int b0 = 0; b0 < B_; b0 += nbg){
    k_sexp<<<144*nbg, 256, 0, stream>>>(qw, kw, Pl, lsum_part, b0, bsh);
    k_pv<<<144*nbg, 256, 0, stream>>>(vw, Pl, lsum_part, x, gm, out, b0, bsh);
  }
}